// Round 1
// baseline (999.693 us; speedup 1.0000x reference)
//
#include <hip/hip_runtime.h>
#include <math.h>

#define TDIM   1032
#define DIM    1024
#define SLEN   2048
#define BATCH  2
#define NROWS  (SLEN*BATCH)   // 4096
#define NHEAD  16
#define HD     64

// ---------------------------------------------------------------------------
// Kernel 1: W[t][o][i] = sum_{dy,dx} cw_t[dy][dx]*tmpl[o+dy][i+dx] + cb_t
// ---------------------------------------------------------------------------
__global__ __launch_bounds__(256) void conv_weight_kernel(
    const float* __restrict__ tmpl,
    const float* __restrict__ cw0, const float* __restrict__ cb0,
    const float* __restrict__ cw1, const float* __restrict__ cb1,
    const float* __restrict__ cw2, const float* __restrict__ cb2,
    float* __restrict__ W)
{
    int t = blockIdx.z;
    const float* cw = (t == 0) ? cw0 : ((t == 1) ? cw1 : cw2);
    const float* cb = (t == 0) ? cb0 : ((t == 1) ? cb1 : cb2);
    __shared__ float scw[81];
    if (threadIdx.x < 81) scw[threadIdx.x] = cw[threadIdx.x];
    __syncthreads();
    int i = blockIdx.x * 256 + threadIdx.x;
    int o = blockIdx.y;
    float acc = cb[0];
    #pragma unroll
    for (int dy = 0; dy < 9; ++dy) {
        const float* trow = tmpl + (size_t)(o + dy) * TDIM + i;
        #pragma unroll
        for (int dx = 0; dx < 9; ++dx)
            acc = fmaf(scw[dy * 9 + dx], trow[dx], acc);
    }
    W[(size_t)t * DIM * DIM + (size_t)o * DIM + i] = acc;
}

// ---------------------------------------------------------------------------
// Kernel 2: Y[t] = X[t] @ W[t]^T + bias[t].  X:[4096,1024], W:[1024,1024]
// 64x64 tile, BK=64, 256 threads, 4x4 micro-tile, k-major LDS (stride 68).
// ---------------------------------------------------------------------------
#define LSTR 68

__global__ __launch_bounds__(256) void qkv_gemm_kernel(
    const float* __restrict__ x0, const float* __restrict__ x1,
    const float* __restrict__ x2,
    const float* __restrict__ Wall,
    const float* __restrict__ b0, const float* __restrict__ b1,
    const float* __restrict__ b2,
    float* __restrict__ Yall)
{
    int t = blockIdx.z;
    const float* X    = (t == 0) ? x0 : ((t == 1) ? x1 : x2);
    const float* Wt   = Wall + (size_t)t * DIM * DIM;
    const float* bias = (t == 0) ? b0 : ((t == 1) ? b1 : b2);
    float* Y = Yall + (size_t)t * NROWS * DIM;

    __shared__ float As[64][LSTR];  // As[k][m]
    __shared__ float Bs[64][LSTR];  // Bs[k][n]

    int tid = threadIdx.x;
    int tx = tid & 15, ty = tid >> 4;
    int m0 = blockIdx.y * 64;
    int n0 = blockIdx.x * 64;

    float acc[4][4] = {};

    for (int k0 = 0; k0 < DIM; k0 += 64) {
        #pragma unroll
        for (int j = 0; j < 4; ++j) {
            int r = ty + 16 * j;
            float4 a = *(const float4*)(X + (size_t)(m0 + r) * DIM + k0 + tx * 4);
            As[tx * 4 + 0][r] = a.x; As[tx * 4 + 1][r] = a.y;
            As[tx * 4 + 2][r] = a.z; As[tx * 4 + 3][r] = a.w;
            float4 bv = *(const float4*)(Wt + (size_t)(n0 + r) * DIM + k0 + tx * 4);
            Bs[tx * 4 + 0][r] = bv.x; Bs[tx * 4 + 1][r] = bv.y;
            Bs[tx * 4 + 2][r] = bv.z; Bs[tx * 4 + 3][r] = bv.w;
        }
        __syncthreads();
        #pragma unroll 8
        for (int k = 0; k < 64; ++k) {
            float4 av = *(const float4*)&As[k][ty * 4];
            float4 bv = *(const float4*)&Bs[k][tx * 4];
            float a[4] = {av.x, av.y, av.z, av.w};
            float bb[4] = {bv.x, bv.y, bv.z, bv.w};
            #pragma unroll
            for (int i = 0; i < 4; ++i)
                #pragma unroll
                for (int j = 0; j < 4; ++j)
                    acc[i][j] = fmaf(a[i], bb[j], acc[i][j]);
        }
        __syncthreads();
    }

    #pragma unroll
    for (int i = 0; i < 4; ++i) {
        int m = m0 + ty * 4 + i;
        int n = n0 + tx * 4;
        float4 o;
        o.x = acc[i][0] + bias[n + 0];
        o.y = acc[i][1] + bias[n + 1];
        o.z = acc[i][2] + bias[n + 2];
        o.w = acc[i][3] + bias[n + 3];
        *(float4*)(Y + (size_t)m * DIM + n) = o;
    }
}

// ---------------------------------------------------------------------------
// Kernel 3: flash attention, fp32. One block = (b, h, 64-query tile).
// ---------------------------------------------------------------------------
__global__ __launch_bounds__(256) void attn_kernel(
    const float* __restrict__ QKV, float* __restrict__ out)
{
    const float* Qp = QKV;
    const float* Kp = QKV + (size_t)NROWS * DIM;
    const float* Vp = QKV + 2 * (size_t)NROWS * DIM;

    int b  = blockIdx.z;
    int h  = blockIdx.y;
    int q0 = blockIdx.x * 64;
    int tid = threadIdx.x;
    int tx = tid & 15, ty = tid >> 4;

    __shared__ float Qs[64][LSTR];   // Qs[d][m]
    __shared__ float Ks[64][LSTR];   // Ks[d][n]
    __shared__ float Ss[64][LSTR];   // Ss[m][n]
    __shared__ float Vs[64][LSTR];   // Vs[n][d]
    __shared__ float red[4][64];
    __shared__ float rowm[64], rowl[64], rowalpha[64];

    // load Q tile (transposed into Qs[d][m])
    #pragma unroll
    for (int j = 0; j < 4; ++j) {
        int m = ty + 16 * j;
        const float* src = Qp + (size_t)((q0 + m) * BATCH + b) * DIM + h * HD + tx * 4;
        float4 qv = *(const float4*)src;
        Qs[tx * 4 + 0][m] = qv.x; Qs[tx * 4 + 1][m] = qv.y;
        Qs[tx * 4 + 2][m] = qv.z; Qs[tx * 4 + 3][m] = qv.w;
    }
    if (tid < 64) { rowm[tid] = -1e30f; rowl[tid] = 0.0f; }

    float acc[4][4] = {};

    for (int kt = 0; kt < SLEN / 64; ++kt) {
        int n0 = kt * 64;
        // load K (transposed) and V (row-major) tiles
        #pragma unroll
        for (int j = 0; j < 4; ++j) {
            int n = ty + 16 * j;
            size_t grow = (size_t)((n0 + n) * BATCH + b) * DIM + h * HD + tx * 4;
            float4 kv = *(const float4*)(Kp + grow);
            Ks[tx * 4 + 0][n] = kv.x; Ks[tx * 4 + 1][n] = kv.y;
            Ks[tx * 4 + 2][n] = kv.z; Ks[tx * 4 + 3][n] = kv.w;
            float4 vv = *(const float4*)(Vp + grow);
            *(float4*)&Vs[n][tx * 4] = vv;
        }
        __syncthreads();   // sync1: tiles ready (also guards Ss overwrite below)

        // S = Q K^T / 8
        float sacc[4][4] = {};
        #pragma unroll 8
        for (int d = 0; d < 64; ++d) {
            float4 qv = *(const float4*)&Qs[d][ty * 4];
            float4 kv = *(const float4*)&Ks[d][tx * 4];
            float a[4] = {qv.x, qv.y, qv.z, qv.w};
            float bb[4] = {kv.x, kv.y, kv.z, kv.w};
            #pragma unroll
            for (int i = 0; i < 4; ++i)
                #pragma unroll
                for (int j = 0; j < 4; ++j)
                    sacc[i][j] = fmaf(a[i], bb[j], sacc[i][j]);
        }
        #pragma unroll
        for (int i = 0; i < 4; ++i) {
            float4 sv;
            sv.x = sacc[i][0] * 0.125f; sv.y = sacc[i][1] * 0.125f;
            sv.z = sacc[i][2] * 0.125f; sv.w = sacc[i][3] * 0.125f;
            *(float4*)&Ss[ty * 4 + i][tx * 4] = sv;
        }
        __syncthreads();   // sync2: Ss written

        // online softmax: partial max
        int r = tid & 63, c = tid >> 6;
        float pm = -1e30f;
        #pragma unroll
        for (int k = 0; k < 16; ++k) pm = fmaxf(pm, Ss[r][c * 16 + k]);
        red[c][r] = pm;
        __syncthreads();   // sync3
        if (tid < 64) {
            float mn = fmaxf(fmaxf(red[0][tid], red[1][tid]),
                             fmaxf(red[2][tid], red[3][tid]));
            mn = fmaxf(mn, rowm[tid]);
            rowalpha[tid] = __expf(rowm[tid] - mn);
            rowm[tid] = mn;
        }
        __syncthreads();   // sync4: rowm/rowalpha ready

        // exp + partial sum (in place)
        float mn = rowm[r];
        float ps = 0.0f;
        #pragma unroll
        for (int k = 0; k < 16; ++k) {
            float e = __expf(Ss[r][c * 16 + k] - mn);
            Ss[r][c * 16 + k] = e;
            ps += e;
        }
        red[c][r] = ps;
        __syncthreads();   // sync5: exp'd Ss + partial sums ready
        if (tid < 64) {
            rowl[tid] = rowl[tid] * rowalpha[tid] +
                        red[0][tid] + red[1][tid] + red[2][tid] + red[3][tid];
        }

        // rescale accumulator, then O += P V
        float al[4];
        #pragma unroll
        for (int i = 0; i < 4; ++i) al[i] = rowalpha[ty * 4 + i];
        #pragma unroll
        for (int i = 0; i < 4; ++i)
            #pragma unroll
            for (int j = 0; j < 4; ++j) acc[i][j] *= al[i];

        #pragma unroll 8
        for (int n = 0; n < 64; ++n) {
            float p0 = Ss[ty * 4 + 0][n];
            float p1 = Ss[ty * 4 + 1][n];
            float p2 = Ss[ty * 4 + 2][n];
            float p3 = Ss[ty * 4 + 3][n];
            float4 vv = *(const float4*)&Vs[n][tx * 4];
            acc[0][0] = fmaf(p0, vv.x, acc[0][0]);
            acc[0][1] = fmaf(p0, vv.y, acc[0][1]);
            acc[0][2] = fmaf(p0, vv.z, acc[0][2]);
            acc[0][3] = fmaf(p0, vv.w, acc[0][3]);
            acc[1][0] = fmaf(p1, vv.x, acc[1][0]);
            acc[1][1] = fmaf(p1, vv.y, acc[1][1]);
            acc[1][2] = fmaf(p1, vv.z, acc[1][2]);
            acc[1][3] = fmaf(p1, vv.w, acc[1][3]);
            acc[2][0] = fmaf(p2, vv.x, acc[2][0]);
            acc[2][1] = fmaf(p2, vv.y, acc[2][1]);
            acc[2][2] = fmaf(p2, vv.z, acc[2][2]);
            acc[2][3] = fmaf(p2, vv.w, acc[2][3]);
            acc[3][0] = fmaf(p3, vv.x, acc[3][0]);
            acc[3][1] = fmaf(p3, vv.y, acc[3][1]);
            acc[3][2] = fmaf(p3, vv.z, acc[3][2]);
            acc[3][3] = fmaf(p3, vv.w, acc[3][3]);
        }
        __syncthreads();   // sync6: done with Ss/Ks/Vs/red for this tile
    }

    // epilogue: divide by l, store
    float rl[4];
    #pragma unroll
    for (int i = 0; i < 4; ++i) rl[i] = 1.0f / rowl[ty * 4 + i];
    #pragma unroll
    for (int i = 0; i < 4; ++i) {
        int m = q0 + ty * 4 + i;
        float* dst = out + (size_t)(m * BATCH + b) * DIM + h * HD + tx * 4;
        float4 o;
        o.x = acc[i][0] * rl[i]; o.y = acc[i][1] * rl[i];
        o.z = acc[i][2] * rl[i]; o.w = acc[i][3] * rl[i];
        *(float4*)dst = o;
    }
}

// ---------------------------------------------------------------------------
extern "C" void kernel_launch(void* const* d_in, const int* in_sizes, int n_in,
                              void* d_out, int out_size, void* d_ws, size_t ws_size,
                              hipStream_t stream)
{
    const float* query = (const float*)d_in[0];
    const float* key_  = (const float*)d_in[1];
    const float* value = (const float*)d_in[2];
    const float* tmpl  = (const float*)d_in[3];
    const float* wq_cw = (const float*)d_in[4];
    const float* wq_cb = (const float*)d_in[5];
    const float* wq_b  = (const float*)d_in[6];
    const float* wk_cw = (const float*)d_in[7];
    const float* wk_cb = (const float*)d_in[8];
    const float* wk_b  = (const float*)d_in[9];
    const float* wv_cw = (const float*)d_in[10];
    const float* wv_cb = (const float*)d_in[11];
    const float* wv_b  = (const float*)d_in[12];

    float* W   = (float*)d_ws;                       // 3 * 1024 * 1024
    float* QKV = (float*)d_ws + (size_t)3 * DIM * DIM; // 3 * 4096 * 1024
    float* out = (float*)d_out;

    conv_weight_kernel<<<dim3(DIM / 256, DIM, 3), 256, 0, stream>>>(
        tmpl, wq_cw, wq_cb, wk_cw, wk_cb, wv_cw, wv_cb, W);

    qkv_gemm_kernel<<<dim3(DIM / 64, NROWS / 64, 3), 256, 0, stream>>>(
        query, key_, value, W, wq_b, wk_b, wv_b, QKV);

    attn_kernel<<<dim3(SLEN / 64, NHEAD, BATCH), 256, 0, stream>>>(QKV, out);
}

// Round 2
// 689.337 us; speedup vs baseline: 1.4502x; 1.4502x over previous
//
#include <hip/hip_runtime.h>
#include <math.h>

#define TDIM   1032
#define DIM    1024
#define SLEN   2048
#define BATCH  2
#define NROWS  (SLEN*BATCH)   // 4096
#define NHEAD  16
#define HD     64

typedef short short8 __attribute__((ext_vector_type(8)));
typedef float f32x4  __attribute__((ext_vector_type(4)));

__device__ inline unsigned short f2bf_rne(float x) {
    union { float f; unsigned u; } v; v.f = x;
    unsigned r = v.u + 0x7fffu + ((v.u >> 16) & 1u);
    return (unsigned short)(r >> 16);
}
__device__ inline float bf2f(unsigned short b) {
    union { unsigned u; float f; } v; v.u = ((unsigned)b) << 16;
    return v.f;
}

// ---------------------------------------------------------------------------
// Kernel 1: W[t][o][i] = conv9x9(template) + conv bias   (fp32)
// ---------------------------------------------------------------------------
__global__ __launch_bounds__(256) void conv_weight_kernel(
    const float* __restrict__ tmpl,
    const float* __restrict__ cw0, const float* __restrict__ cb0,
    const float* __restrict__ cw1, const float* __restrict__ cb1,
    const float* __restrict__ cw2, const float* __restrict__ cb2,
    float* __restrict__ W)
{
    int t = blockIdx.z;
    const float* cw = (t == 0) ? cw0 : ((t == 1) ? cw1 : cw2);
    const float* cb = (t == 0) ? cb0 : ((t == 1) ? cb1 : cb2);
    __shared__ float scw[81];
    if (threadIdx.x < 81) scw[threadIdx.x] = cw[threadIdx.x];
    __syncthreads();
    int i = blockIdx.x * 256 + threadIdx.x;
    int o = blockIdx.y;
    float acc = cb[0];
    #pragma unroll
    for (int dy = 0; dy < 9; ++dy) {
        const float* trow = tmpl + (size_t)(o + dy) * TDIM + i;
        #pragma unroll
        for (int dx = 0; dx < 9; ++dx)
            acc = fmaf(scw[dy * 9 + dx], trow[dx], acc);
    }
    W[(size_t)t * DIM * DIM + (size_t)o * DIM + i] = acc;
}

// ---------------------------------------------------------------------------
// Kernel 2: fp32 GEMM Y = X @ W^T + b.  Epilogue: t<2 -> bf16 hi/lo split
// (Qh/Ql or Kh/Kl), t==2 -> fp32 V.
// ---------------------------------------------------------------------------
#define LSTR 68

__global__ __launch_bounds__(256) void qkv_gemm_kernel(
    const float* __restrict__ x0, const float* __restrict__ x1,
    const float* __restrict__ x2,
    const float* __restrict__ Wall,
    const float* __restrict__ b0, const float* __restrict__ b1,
    const float* __restrict__ b2,
    unsigned short* __restrict__ Qh, unsigned short* __restrict__ Ql,
    unsigned short* __restrict__ Kh, unsigned short* __restrict__ Kl,
    float* __restrict__ Vf)
{
    int t = blockIdx.z;
    const float* X    = (t == 0) ? x0 : ((t == 1) ? x1 : x2);
    const float* Wt   = Wall + (size_t)t * DIM * DIM;
    const float* bias = (t == 0) ? b0 : ((t == 1) ? b1 : b2);
    unsigned short* Yh = (t == 0) ? Qh : Kh;
    unsigned short* Yl = (t == 0) ? Ql : Kl;

    __shared__ float As[64][LSTR];  // As[k][m]
    __shared__ float Bs[64][LSTR];  // Bs[k][n]

    int tid = threadIdx.x;
    int tx = tid & 15, ty = tid >> 4;
    int m0 = blockIdx.y * 64;
    int n0 = blockIdx.x * 64;

    float acc[4][4] = {};

    for (int k0 = 0; k0 < DIM; k0 += 64) {
        #pragma unroll
        for (int j = 0; j < 4; ++j) {
            int r = ty + 16 * j;
            float4 a = *(const float4*)(X + (size_t)(m0 + r) * DIM + k0 + tx * 4);
            As[tx * 4 + 0][r] = a.x; As[tx * 4 + 1][r] = a.y;
            As[tx * 4 + 2][r] = a.z; As[tx * 4 + 3][r] = a.w;
            float4 bv = *(const float4*)(Wt + (size_t)(n0 + r) * DIM + k0 + tx * 4);
            Bs[tx * 4 + 0][r] = bv.x; Bs[tx * 4 + 1][r] = bv.y;
            Bs[tx * 4 + 2][r] = bv.z; Bs[tx * 4 + 3][r] = bv.w;
        }
        __syncthreads();
        #pragma unroll 8
        for (int k = 0; k < 64; ++k) {
            float4 av = *(const float4*)&As[k][ty * 4];
            float4 bv = *(const float4*)&Bs[k][tx * 4];
            float a[4] = {av.x, av.y, av.z, av.w};
            float bb[4] = {bv.x, bv.y, bv.z, bv.w};
            #pragma unroll
            for (int i = 0; i < 4; ++i)
                #pragma unroll
                for (int j = 0; j < 4; ++j)
                    acc[i][j] = fmaf(a[i], bb[j], acc[i][j]);
        }
        __syncthreads();
    }

    #pragma unroll
    for (int i = 0; i < 4; ++i) {
        int m = m0 + ty * 4 + i;
        int n = n0 + tx * 4;
        float o[4];
        #pragma unroll
        for (int j = 0; j < 4; ++j) o[j] = acc[i][j] + bias[n + j];
        if (t < 2) {
            ushort4 hv, lv;
            unsigned short h0 = f2bf_rne(o[0]), h1 = f2bf_rne(o[1]),
                           h2 = f2bf_rne(o[2]), h3 = f2bf_rne(o[3]);
            hv.x = h0; hv.y = h1; hv.z = h2; hv.w = h3;
            lv.x = f2bf_rne(o[0] - bf2f(h0));
            lv.y = f2bf_rne(o[1] - bf2f(h1));
            lv.z = f2bf_rne(o[2] - bf2f(h2));
            lv.w = f2bf_rne(o[3] - bf2f(h3));
            *(ushort4*)(Yh + (size_t)m * DIM + n) = hv;
            *(ushort4*)(Yl + (size_t)m * DIM + n) = lv;
        } else {
            float4 ov; ov.x = o[0]; ov.y = o[1]; ov.z = o[2]; ov.w = o[3];
            *(float4*)(Vf + (size_t)m * DIM + n) = ov;
        }
    }
}

// ---------------------------------------------------------------------------
// Kernel 3: V fp32 [s*B+b][h*64+d]  ->  Vt bf16 [b][h][d][s]
// ---------------------------------------------------------------------------
__global__ __launch_bounds__(256) void vt_kernel(
    const float* __restrict__ Vf, unsigned short* __restrict__ Vt)
{
    int b = blockIdx.z, h = blockIdx.y, s0 = blockIdx.x * 64;
    __shared__ float tile[64][65];   // [d][s_local]
    int tid = threadIdx.x;
    int sl = tid >> 2, d0 = (tid & 3) * 16;
    const float* src = Vf + (size_t)((s0 + sl) * BATCH + b) * DIM + h * HD + d0;
    #pragma unroll
    for (int j = 0; j < 4; ++j) {
        float4 v = *(const float4*)(src + j * 4);
        tile[d0 + j * 4 + 0][sl] = v.x;
        tile[d0 + j * 4 + 1][sl] = v.y;
        tile[d0 + j * 4 + 2][sl] = v.z;
        tile[d0 + j * 4 + 3][sl] = v.w;
    }
    __syncthreads();
    int d = tid >> 2, sc0 = (tid & 3) * 16;
    unsigned short* dst = Vt + (size_t)((b * NHEAD + h) * HD + d) * SLEN + s0 + sc0;
    #pragma unroll
    for (int g = 0; g < 4; ++g) {
        ushort4 o;
        o.x = f2bf_rne(tile[d][sc0 + g * 4 + 0]);
        o.y = f2bf_rne(tile[d][sc0 + g * 4 + 1]);
        o.z = f2bf_rne(tile[d][sc0 + g * 4 + 2]);
        o.w = f2bf_rne(tile[d][sc0 + g * 4 + 3]);
        *(ushort4*)(dst + g * 4) = o;
    }
}

// ---------------------------------------------------------------------------
// Kernel 4: MFMA flash attention.
// Block = (b, h, 64-query tile), 4 waves; wave w owns q-rows w*16..w*16+15.
// QK^T: 3-term bf16 hi/lo split. Softmax state per-row in registers
// (shfl_xor over the 16-lane quad group). P -> bf16 -> wave-private LDS
// (C-layout -> A-layout). PV: plain bf16 MFMA with V^T tiles.
// ---------------------------------------------------------------------------
#define KPAD 72   // ushort stride (144B) for K/V LDS rows
#define PPAD 72   // ushort stride (144B) for P rows (16B-aligned b128 reads)

__global__ __launch_bounds__(256) void attn_mfma_kernel(
    const unsigned short* __restrict__ Qh, const unsigned short* __restrict__ Ql,
    const unsigned short* __restrict__ Kh, const unsigned short* __restrict__ Kl,
    const unsigned short* __restrict__ Vt, float* __restrict__ out)
{
    int b = blockIdx.z, h = blockIdx.y;
    int q0 = blockIdx.x * 64;
    int tid = threadIdx.x;
    int w = tid >> 6, lane = tid & 63;
    int c = lane & 15, quad = lane >> 4;

    __shared__ __align__(16) unsigned short sKh[64 * KPAD];
    __shared__ __align__(16) unsigned short sKl[64 * KPAD];
    __shared__ __align__(16) unsigned short sVt[64 * KPAD];
    __shared__ __align__(16) unsigned short sP[4][16 * PPAD];

    // --- Q fragments (A-operand: m = lane&15, k-chunk = quad*8, 2 k-steps) ---
    short8 qhf[2], qlf[2];
    {
        int s = q0 + w * 16 + c;
        size_t base = (size_t)(s * BATCH + b) * DIM + h * HD + quad * 8;
        qhf[0] = *(const short8*)(Qh + base);
        qhf[1] = *(const short8*)(Qh + base + 32);
        qlf[0] = *(const short8*)(Ql + base);
        qlf[1] = *(const short8*)(Ql + base + 32);
    }

    f32x4 acc[4];   // O accumulator: 4 d-tiles x 4 rows (C-layout)
    #pragma unroll
    for (int i = 0; i < 4; ++i)
        #pragma unroll
        for (int j = 0; j < 4; ++j) acc[i][j] = 0.0f;
    float m_run[4], l_run[4];
    #pragma unroll
    for (int r = 0; r < 4; ++r) { m_run[r] = -1e38f; l_run[r] = 0.0f; }

    const float cs = 0.125f * 1.44269504f;  // fold 1/sqrt(64) into exp2

    int r8 = lane >> 3, c8 = lane & 7;      // staging decode

    for (int n0 = 0; n0 < SLEN; n0 += 64) {
        // ---- stage Khi/Klo/Vt tiles into LDS (24 wave-instrs, 6 per wave) ----
        short8 stg[6];
        #pragma unroll
        for (int i = 0; i < 6; ++i) {
            int idx = w * 6 + i;
            int a = idx >> 3, sub = idx & 7;
            int row = sub * 8 + r8;
            if (a < 2) {
                const unsigned short* src = (a == 0) ? Kh : Kl;
                size_t g = (size_t)((n0 + row) * BATCH + b) * DIM + h * HD + c8 * 8;
                stg[i] = *(const short8*)(src + g);
            } else {
                size_t g = (size_t)((b * NHEAD + h) * HD + row) * SLEN + n0 + c8 * 8;
                stg[i] = *(const short8*)(Vt + g);
            }
        }
        #pragma unroll
        for (int i = 0; i < 6; ++i) {
            int idx = w * 6 + i;
            int a = idx >> 3, sub = idx & 7;
            int row = sub * 8 + r8;
            unsigned short* dst = (a == 0) ? sKh : ((a == 1) ? sKl : sVt);
            *(short8*)(dst + row * KPAD + c8 * 8) = stg[i];
        }
        __syncthreads();

        // ---- S = Q K^T (raw scale), 4 col-tiles, 3-term split ----
        f32x4 sc[4];
        #pragma unroll
        for (int ct = 0; ct < 4; ++ct) {
            #pragma unroll
            for (int j = 0; j < 4; ++j) sc[ct][j] = 0.0f;
            int kb = (ct * 16 + c) * KPAD + quad * 8;
            short8 kh0 = *(short8*)(sKh + kb);
            short8 kh1 = *(short8*)(sKh + kb + 32);
            short8 kl0 = *(short8*)(sKl + kb);
            short8 kl1 = *(short8*)(sKl + kb + 32);
            sc[ct] = __builtin_amdgcn_mfma_f32_16x16x32_bf16(qhf[0], kh0, sc[ct], 0, 0, 0);
            sc[ct] = __builtin_amdgcn_mfma_f32_16x16x32_bf16(qhf[1], kh1, sc[ct], 0, 0, 0);
            sc[ct] = __builtin_amdgcn_mfma_f32_16x16x32_bf16(qhf[0], kl0, sc[ct], 0, 0, 0);
            sc[ct] = __builtin_amdgcn_mfma_f32_16x16x32_bf16(qhf[1], kl1, sc[ct], 0, 0, 0);
            sc[ct] = __builtin_amdgcn_mfma_f32_16x16x32_bf16(qlf[0], kh0, sc[ct], 0, 0, 0);
            sc[ct] = __builtin_amdgcn_mfma_f32_16x16x32_bf16(qlf[1], kh1, sc[ct], 0, 0, 0);
        }

        // ---- online softmax (rows quad*4+r, reduce across 16-lane group) ----
        #pragma unroll
        for (int r = 0; r < 4; ++r) {
            float t = fmaxf(fmaxf(sc[0][r], sc[1][r]), fmaxf(sc[2][r], sc[3][r]));
            t = fmaxf(t, __shfl_xor(t, 1));
            t = fmaxf(t, __shfl_xor(t, 2));
            t = fmaxf(t, __shfl_xor(t, 4));
            t = fmaxf(t, __shfl_xor(t, 8));
            float mnew = fmaxf(m_run[r], t);
            float al = exp2f((m_run[r] - mnew) * cs);
            m_run[r] = mnew;
            float rs = 0.0f;
            #pragma unroll
            for (int ct = 0; ct < 4; ++ct) {
                float p = exp2f((sc[ct][r] - mnew) * cs);
                sc[ct][r] = p;
                rs += p;
            }
            rs += __shfl_xor(rs, 1);
            rs += __shfl_xor(rs, 2);
            rs += __shfl_xor(rs, 4);
            rs += __shfl_xor(rs, 8);
            l_run[r] = l_run[r] * al + rs;
            #pragma unroll
            for (int ctd = 0; ctd < 4; ++ctd) acc[ctd][r] *= al;
        }

        // ---- P (C-layout) -> bf16 -> wave-private LDS (A-layout rows) ----
        #pragma unroll
        for (int ct = 0; ct < 4; ++ct)
            #pragma unroll
            for (int r = 0; r < 4; ++r)
                sP[w][(quad * 4 + r) * PPAD + ct * 16 + c] = f2bf_rne(sc[ct][r]);

        // ---- O += P V : A-frags from sP, B-frags (V^T) from sVt ----
        short8 pf0 = *(short8*)(sP[w] + c * PPAD + quad * 8);
        short8 pf1 = *(short8*)(sP[w] + c * PPAD + 32 + quad * 8);
        #pragma unroll
        for (int ctd = 0; ctd < 4; ++ctd) {
            int vb = (ctd * 16 + c) * KPAD + quad * 8;
            short8 v0 = *(short8*)(sVt + vb);
            short8 v1 = *(short8*)(sVt + vb + 32);
            acc[ctd] = __builtin_amdgcn_mfma_f32_16x16x32_bf16(pf0, v0, acc[ctd], 0, 0, 0);
            acc[ctd] = __builtin_amdgcn_mfma_f32_16x16x32_bf16(pf1, v1, acc[ctd], 0, 0, 0);
        }
        __syncthreads();   // protect K/V LDS before next stage
    }

    // ---- epilogue: divide by l, store (C-layout: row quad*4+r, col = c) ----
    float rl[4];
    #pragma unroll
    for (int r = 0; r < 4; ++r) rl[r] = 1.0f / l_run[r];
    #pragma unroll
    for (int ctd = 0; ctd < 4; ++ctd) {
        #pragma unroll
        for (int r = 0; r < 4; ++r) {
            int s = q0 + w * 16 + quad * 4 + r;
            out[(size_t)(s * BATCH + b) * DIM + h * HD + ctd * 16 + c] =
                acc[ctd][r] * rl[r];
        }
    }
}

// ---------------------------------------------------------------------------
extern "C" void kernel_launch(void* const* d_in, const int* in_sizes, int n_in,
                              void* d_out, int out_size, void* d_ws, size_t ws_size,
                              hipStream_t stream)
{
    const float* query = (const float*)d_in[0];
    const float* key_  = (const float*)d_in[1];
    const float* value = (const float*)d_in[2];
    const float* tmpl  = (const float*)d_in[3];
    const float* wq_cw = (const float*)d_in[4];
    const float* wq_cb = (const float*)d_in[5];
    const float* wq_b  = (const float*)d_in[6];
    const float* wk_cw = (const float*)d_in[7];
    const float* wk_cb = (const float*)d_in[8];
    const float* wk_b  = (const float*)d_in[9];
    const float* wv_cw = (const float*)d_in[10];
    const float* wv_cb = (const float*)d_in[11];
    const float* wv_b  = (const float*)d_in[12];

    char* ws = (char*)d_ws;
    float*          W  = (float*)(ws);                      // 12,582,912 B
    unsigned short* Qh = (unsigned short*)(ws + 12582912);  //  8,388,608 B
    unsigned short* Ql = (unsigned short*)(ws + 20971520);
    unsigned short* Kh = (unsigned short*)(ws + 29360128);
    unsigned short* Kl = (unsigned short*)(ws + 37748736);
    float*          Vf = (float*)(ws + 46137344);           // 16,777,216 B
    unsigned short* Vt = (unsigned short*)(ws + 62914560);  //  8,388,608 B
    float* out = (float*)d_out;

    conv_weight_kernel<<<dim3(DIM / 256, DIM, 3), 256, 0, stream>>>(
        tmpl, wq_cw, wq_cb, wk_cw, wk_cb, wv_cw, wv_cb, W);

    qkv_gemm_kernel<<<dim3(DIM / 64, NROWS / 64, 3), 256, 0, stream>>>(
        query, key_, value, W, wq_b, wk_b, wv_b, Qh, Ql, Kh, Kl, Vf);

    vt_kernel<<<dim3(SLEN / 64, NHEAD, BATCH), 256, 0, stream>>>(Vf, Vt);

    attn_mfma_kernel<<<dim3(SLEN / 64, NHEAD, BATCH), 256, 0, stream>>>(
        Qh, Ql, Kh, Kl, Vt, out);
}

// Round 3
// 411.114 us; speedup vs baseline: 2.4317x; 1.6768x over previous
//
#include <hip/hip_runtime.h>
#include <math.h>

#define TDIM   1032
#define DIM    1024
#define SLEN   2048
#define BATCH  2
#define NROWS  (SLEN*BATCH)   // 4096
#define NHEAD  16
#define HD     64

typedef unsigned short u16;
typedef short short8 __attribute__((ext_vector_type(8)));
typedef float f32x4  __attribute__((ext_vector_type(4)));

__device__ inline u16 f2bf_rne(float x) {
    union { float f; unsigned u; } v; v.f = x;
    unsigned r = v.u + 0x7fffu + ((v.u >> 16) & 1u);
    return (u16)(r >> 16);
}
__device__ inline float bf2f(u16 b) {
    union { unsigned u; float f; } v; v.u = ((unsigned)b) << 16;
    return v.f;
}
__device__ inline void async_copy16(const void* g, void* l) {
    __builtin_amdgcn_global_load_lds(
        (const __attribute__((address_space(1))) void*)g,
        (__attribute__((address_space(3))) void*)l, 16, 0, 0);
}

// ---------------------------------------------------------------------------
// Kernel 1: conv 9x9 over template -> Wh/Wl bf16 hi/lo split directly.
// ---------------------------------------------------------------------------
__global__ __launch_bounds__(256) void conv_weight_kernel(
    const float* __restrict__ tmpl,
    const float* __restrict__ cw0, const float* __restrict__ cb0,
    const float* __restrict__ cw1, const float* __restrict__ cb1,
    const float* __restrict__ cw2, const float* __restrict__ cb2,
    u16* __restrict__ Wh, u16* __restrict__ Wl)
{
    int t = blockIdx.z;
    const float* cw = (t == 0) ? cw0 : ((t == 1) ? cw1 : cw2);
    const float* cb = (t == 0) ? cb0 : ((t == 1) ? cb1 : cb2);
    __shared__ float scw[81];
    if (threadIdx.x < 81) scw[threadIdx.x] = cw[threadIdx.x];
    __syncthreads();
    int i = blockIdx.x * 256 + threadIdx.x;
    int o = blockIdx.y;
    float acc = cb[0];
    #pragma unroll
    for (int dy = 0; dy < 9; ++dy) {
        const float* trow = tmpl + (size_t)(o + dy) * TDIM + i;
        #pragma unroll
        for (int dx = 0; dx < 9; ++dx)
            acc = fmaf(scw[dy * 9 + dx], trow[dx], acc);
    }
    size_t idx = (size_t)t * DIM * DIM + (size_t)o * DIM + i;
    u16 h = f2bf_rne(acc);
    Wh[idx] = h;
    Wl[idx] = f2bf_rne(acc - bf2f(h));
}

// ---------------------------------------------------------------------------
// Kernel 2: MFMA GEMM  Y[t] = X[t] @ W[t]^T + b[t]   (3-term bf16 hi/lo)
// 128x128 tile, BK=32, 4 waves (2x2 of 64x64), 4x4 acc tiles per wave.
// B (Wh/Wl) staged via global_load_lds width=16; A staged fp32->hi/lo via
// registers. DMA/loads for it+1 issued before the 48 MFMAs of it.
// t<2 -> Yh/Yl bf16 hi/lo; t==2 -> V bf16.
// ---------------------------------------------------------------------------
__global__ __launch_bounds__(256, 3) void qkv_mfma_gemm(
    const float* __restrict__ x0, const float* __restrict__ x1,
    const float* __restrict__ x2,
    const u16* __restrict__ Whg, const u16* __restrict__ Wlg,
    const float* __restrict__ b0, const float* __restrict__ b1,
    const float* __restrict__ b2,
    u16* __restrict__ Qh, u16* __restrict__ Ql,
    u16* __restrict__ Kh, u16* __restrict__ Kl,
    u16* __restrict__ Vb)
{
    int t = blockIdx.z;
    const float* X    = (t == 0) ? x0 : ((t == 1) ? x1 : x2);
    const u16* Bh_g   = Whg + (size_t)t * DIM * DIM;
    const u16* Bl_g   = Wlg + (size_t)t * DIM * DIM;
    const float* bias = (t == 0) ? b0 : ((t == 1) ? b1 : b2);

    // 4 tiles of 128 rows x 32 cols bf16 (8KB each): Ah Al Bh Bl
    __shared__ __align__(16) u16 lds[16384];
    u16* sAh = lds;
    u16* sAl = lds + 4096;
    u16* sBh = lds + 8192;
    u16* sBl = lds + 12288;

    int tid = threadIdx.x;
    int w = tid >> 6, lane = tid & 63;
    int c = lane & 15, quad = lane >> 4;
    int m0 = blockIdx.y * 128, n0 = blockIdx.x * 128;
    int mh = (w >> 1) * 64, nh = (w & 1) * 64;

    // A staging decode: 16 fp32/lane
    int arow = w * 32 + (lane & 31);       // tile row 0..127
    int acol = (lane >> 5) * 16;           // element col 0 or 16
    const float* aptr = X + (size_t)(m0 + arow) * DIM + acol;

    // B DMA decode
    int srow = lane >> 2, sgr = lane & 3;

    f32x4 acc[4][4];
    #pragma unroll
    for (int i = 0; i < 4; ++i)
        #pragma unroll
        for (int j = 0; j < 4; ++j)
            #pragma unroll
            for (int r = 0; r < 4; ++r) acc[i][j][r] = 0.0f;

    float bias_v[4];
    #pragma unroll
    for (int tn = 0; tn < 4; ++tn) bias_v[tn] = bias[n0 + nh + tn * 16 + c];

    float4 xa[4];
    // ---- prologue: stage iter 0 ----
    #pragma unroll
    for (int i = 0; i < 2; ++i) {
        int rb = w * 32 + i * 16;
        const u16* gh = Bh_g + (size_t)(n0 + rb + srow) * DIM + sgr * 8;
        const u16* gl = Bl_g + (size_t)(n0 + rb + srow) * DIM + sgr * 8;
        async_copy16(gh, sBh + rb * 32);
        async_copy16(gl, sBl + rb * 32);
    }
    #pragma unroll
    for (int j = 0; j < 4; ++j) xa[j] = *(const float4*)(aptr + j * 4);

    for (int it = 0; it < 32; ++it) {
        // ---- convert A regs -> hi/lo bf16, write to LDS ----
        #pragma unroll
        for (int g = 0; g < 2; ++g) {
            float v[8] = { xa[2*g].x, xa[2*g].y, xa[2*g].z, xa[2*g].w,
                           xa[2*g+1].x, xa[2*g+1].y, xa[2*g+1].z, xa[2*g+1].w };
            short8 hv, lv;
            #pragma unroll
            for (int e = 0; e < 8; ++e) {
                u16 h = f2bf_rne(v[e]);
                hv[e] = (short)h;
                lv[e] = (short)f2bf_rne(v[e] - bf2f(h));
            }
            *(short8*)(sAh + arow * 32 + acol + g * 8) = hv;
            *(short8*)(sAl + arow * 32 + acol + g * 8) = lv;
        }
        __syncthreads();   // A writes + B DMA complete

        // ---- fragments -> registers ----
        short8 ah[4], al[4], bh[4], bl[4];
        #pragma unroll
        for (int tt = 0; tt < 4; ++tt) {
            int mi = (mh + tt * 16 + c) * 32 + quad * 8;
            ah[tt] = *(short8*)(sAh + mi);
            al[tt] = *(short8*)(sAl + mi);
            int ni = (nh + tt * 16 + c) * 32 + quad * 8;
            bh[tt] = *(short8*)(sBh + ni);
            bl[tt] = *(short8*)(sBl + ni);
        }
        __syncthreads();   // everyone read; LDS free for next stage

        // ---- issue next iter's staging, then do the MFMAs ----
        if (it < 31) {
            int kg = (it + 1) * 4;
            #pragma unroll
            for (int i = 0; i < 2; ++i) {
                int rb = w * 32 + i * 16;
                const u16* gh = Bh_g + (size_t)(n0 + rb + srow) * DIM + (kg + sgr) * 8;
                const u16* gl = Bl_g + (size_t)(n0 + rb + srow) * DIM + (kg + sgr) * 8;
                async_copy16(gh, sBh + rb * 32);
                async_copy16(gl, sBl + rb * 32);
            }
            #pragma unroll
            for (int j = 0; j < 4; ++j)
                xa[j] = *(const float4*)(aptr + (it + 1) * 32 + j * 4);
        }

        #pragma unroll
        for (int tm = 0; tm < 4; ++tm)
            #pragma unroll
            for (int tn = 0; tn < 4; ++tn) {
                acc[tm][tn] = __builtin_amdgcn_mfma_f32_16x16x32_bf16(
                    ah[tm], bh[tn], acc[tm][tn], 0, 0, 0);
                acc[tm][tn] = __builtin_amdgcn_mfma_f32_16x16x32_bf16(
                    ah[tm], bl[tn], acc[tm][tn], 0, 0, 0);
                acc[tm][tn] = __builtin_amdgcn_mfma_f32_16x16x32_bf16(
                    al[tm], bh[tn], acc[tm][tn], 0, 0, 0);
            }
    }

    // ---- epilogue ----
    if (t < 2) {
        u16* Yh = (t == 0) ? Qh : Kh;
        u16* Yl = (t == 0) ? Ql : Kl;
        #pragma unroll
        for (int tm = 0; tm < 4; ++tm)
            #pragma unroll
            for (int r = 0; r < 4; ++r) {
                int m = m0 + mh + tm * 16 + quad * 4 + r;
                #pragma unroll
                for (int tn = 0; tn < 4; ++tn) {
                    int n = n0 + nh + tn * 16 + c;
                    float o = acc[tm][tn][r] + bias_v[tn];
                    u16 h = f2bf_rne(o);
                    Yh[(size_t)m * DIM + n] = h;
                    Yl[(size_t)m * DIM + n] = f2bf_rne(o - bf2f(h));
                }
            }
    } else {
        #pragma unroll
        for (int tm = 0; tm < 4; ++tm)
            #pragma unroll
            for (int r = 0; r < 4; ++r) {
                int m = m0 + mh + tm * 16 + quad * 4 + r;
                #pragma unroll
                for (int tn = 0; tn < 4; ++tn) {
                    int n = n0 + nh + tn * 16 + c;
                    Vb[(size_t)m * DIM + n] = f2bf_rne(acc[tm][tn][r] + bias_v[tn]);
                }
            }
    }
}

// ---------------------------------------------------------------------------
// Kernel 3: V bf16 [s*B+b][h*64+d] -> Vt bf16 [b][h][d][s]
// ---------------------------------------------------------------------------
__global__ __launch_bounds__(256) void vt_kernel(
    const u16* __restrict__ Vb, u16* __restrict__ Vt)
{
    int b = blockIdx.z, h = blockIdx.y, s0 = blockIdx.x * 64;
    __shared__ __align__(16) u16 tile[64][80];
    int tid = threadIdx.x;
    int sl = tid >> 2, d0 = (tid & 3) * 16;
    const u16* src = Vb + (size_t)((s0 + sl) * BATCH + b) * DIM + h * HD + d0;
    short8 v0 = *(const short8*)src;
    short8 v1 = *(const short8*)(src + 8);
    #pragma unroll
    for (int j = 0; j < 8; ++j) {
        tile[d0 + j][sl] = (u16)v0[j];
        tile[d0 + 8 + j][sl] = (u16)v1[j];
    }
    __syncthreads();
    int d = tid >> 2, sc0 = (tid & 3) * 16;
    u16* dst = Vt + (size_t)((b * NHEAD + h) * HD + d) * SLEN + s0 + sc0;
    *(short8*)dst = *(const short8*)&tile[d][sc0];
    *(short8*)(dst + 8) = *(const short8*)&tile[d][sc0 + 8];
}

// ---------------------------------------------------------------------------
// Kernel 4: MFMA flash attention (unchanged from R2 — verified).
// ---------------------------------------------------------------------------
#define KPAD 72
#define PPAD 72

__global__ __launch_bounds__(256) void attn_mfma_kernel(
    const u16* __restrict__ Qh, const u16* __restrict__ Ql,
    const u16* __restrict__ Kh, const u16* __restrict__ Kl,
    const u16* __restrict__ Vt, float* __restrict__ out)
{
    int b = blockIdx.z, h = blockIdx.y;
    int q0 = blockIdx.x * 64;
    int tid = threadIdx.x;
    int w = tid >> 6, lane = tid & 63;
    int c = lane & 15, quad = lane >> 4;

    __shared__ __align__(16) u16 sKh[64 * KPAD];
    __shared__ __align__(16) u16 sKl[64 * KPAD];
    __shared__ __align__(16) u16 sVt[64 * KPAD];
    __shared__ __align__(16) u16 sP[4][16 * PPAD];

    short8 qhf[2], qlf[2];
    {
        int s = q0 + w * 16 + c;
        size_t base = (size_t)(s * BATCH + b) * DIM + h * HD + quad * 8;
        qhf[0] = *(const short8*)(Qh + base);
        qhf[1] = *(const short8*)(Qh + base + 32);
        qlf[0] = *(const short8*)(Ql + base);
        qlf[1] = *(const short8*)(Ql + base + 32);
    }

    f32x4 acc[4];
    #pragma unroll
    for (int i = 0; i < 4; ++i)
        #pragma unroll
        for (int j = 0; j < 4; ++j) acc[i][j] = 0.0f;
    float m_run[4], l_run[4];
    #pragma unroll
    for (int r = 0; r < 4; ++r) { m_run[r] = -1e38f; l_run[r] = 0.0f; }

    const float cs = 0.125f * 1.44269504f;
    int r8 = lane >> 3, c8 = lane & 7;

    for (int n0 = 0; n0 < SLEN; n0 += 64) {
        short8 stg[6];
        #pragma unroll
        for (int i = 0; i < 6; ++i) {
            int idx = w * 6 + i;
            int a = idx >> 3, sub = idx & 7;
            int row = sub * 8 + r8;
            if (a < 2) {
                const u16* src = (a == 0) ? Kh : Kl;
                size_t g = (size_t)((n0 + row) * BATCH + b) * DIM + h * HD + c8 * 8;
                stg[i] = *(const short8*)(src + g);
            } else {
                size_t g = (size_t)((b * NHEAD + h) * HD + row) * SLEN + n0 + c8 * 8;
                stg[i] = *(const short8*)(Vt + g);
            }
        }
        #pragma unroll
        for (int i = 0; i < 6; ++i) {
            int idx = w * 6 + i;
            int a = idx >> 3, sub = idx & 7;
            int row = sub * 8 + r8;
            u16* dst = (a == 0) ? sKh : ((a == 1) ? sKl : sVt);
            *(short8*)(dst + row * KPAD + c8 * 8) = stg[i];
        }
        __syncthreads();

        f32x4 sc[4];
        #pragma unroll
        for (int ct = 0; ct < 4; ++ct) {
            #pragma unroll
            for (int j = 0; j < 4; ++j) sc[ct][j] = 0.0f;
            int kb = (ct * 16 + c) * KPAD + quad * 8;
            short8 kh0 = *(short8*)(sKh + kb);
            short8 kh1 = *(short8*)(sKh + kb + 32);
            short8 kl0 = *(short8*)(sKl + kb);
            short8 kl1 = *(short8*)(sKl + kb + 32);
            sc[ct] = __builtin_amdgcn_mfma_f32_16x16x32_bf16(qhf[0], kh0, sc[ct], 0, 0, 0);
            sc[ct] = __builtin_amdgcn_mfma_f32_16x16x32_bf16(qhf[1], kh1, sc[ct], 0, 0, 0);
            sc[ct] = __builtin_amdgcn_mfma_f32_16x16x32_bf16(qhf[0], kl0, sc[ct], 0, 0, 0);
            sc[ct] = __builtin_amdgcn_mfma_f32_16x16x32_bf16(qhf[1], kl1, sc[ct], 0, 0, 0);
            sc[ct] = __builtin_amdgcn_mfma_f32_16x16x32_bf16(qlf[0], kh0, sc[ct], 0, 0, 0);
            sc[ct] = __builtin_amdgcn_mfma_f32_16x16x32_bf16(qlf[1], kh1, sc[ct], 0, 0, 0);
        }

        #pragma unroll
        for (int r = 0; r < 4; ++r) {
            float t = fmaxf(fmaxf(sc[0][r], sc[1][r]), fmaxf(sc[2][r], sc[3][r]));
            t = fmaxf(t, __shfl_xor(t, 1));
            t = fmaxf(t, __shfl_xor(t, 2));
            t = fmaxf(t, __shfl_xor(t, 4));
            t = fmaxf(t, __shfl_xor(t, 8));
            float mnew = fmaxf(m_run[r], t);
            float al = exp2f((m_run[r] - mnew) * cs);
            m_run[r] = mnew;
            float rs = 0.0f;
            #pragma unroll
            for (int ct = 0; ct < 4; ++ct) {
                float p = exp2f((sc[ct][r] - mnew) * cs);
                sc[ct][r] = p;
                rs += p;
            }
            rs += __shfl_xor(rs, 1);
            rs += __shfl_xor(rs, 2);
            rs += __shfl_xor(rs, 4);
            rs += __shfl_xor(rs, 8);
            l_run[r] = l_run[r] * al + rs;
            #pragma unroll
            for (int ctd = 0; ctd < 4; ++ctd) acc[ctd][r] *= al;
        }

        #pragma unroll
        for (int ct = 0; ct < 4; ++ct)
            #pragma unroll
            for (int r = 0; r < 4; ++r)
                sP[w][(quad * 4 + r) * PPAD + ct * 16 + c] = f2bf_rne(sc[ct][r]);

        short8 pf0 = *(short8*)(sP[w] + c * PPAD + quad * 8);
        short8 pf1 = *(short8*)(sP[w] + c * PPAD + 32 + quad * 8);
        #pragma unroll
        for (int ctd = 0; ctd < 4; ++ctd) {
            int vb = (ctd * 16 + c) * KPAD + quad * 8;
            short8 v0 = *(short8*)(sVt + vb);
            short8 v1 = *(short8*)(sVt + vb + 32);
            acc[ctd] = __builtin_amdgcn_mfma_f32_16x16x32_bf16(pf0, v0, acc[ctd], 0, 0, 0);
            acc[ctd] = __builtin_amdgcn_mfma_f32_16x16x32_bf16(pf1, v1, acc[ctd], 0, 0, 0);
        }
        __syncthreads();
    }

    float rl[4];
    #pragma unroll
    for (int r = 0; r < 4; ++r) rl[r] = 1.0f / l_run[r];
    #pragma unroll
    for (int ctd = 0; ctd < 4; ++ctd) {
        #pragma unroll
        for (int r = 0; r < 4; ++r) {
            int s = q0 + w * 16 + quad * 4 + r;
            out[(size_t)(s * BATCH + b) * DIM + h * HD + ctd * 16 + c] =
                acc[ctd][r] * rl[r];
        }
    }
}

// ---------------------------------------------------------------------------
extern "C" void kernel_launch(void* const* d_in, const int* in_sizes, int n_in,
                              void* d_out, int out_size, void* d_ws, size_t ws_size,
                              hipStream_t stream)
{
    const float* query = (const float*)d_in[0];
    const float* key_  = (const float*)d_in[1];
    const float* value = (const float*)d_in[2];
    const float* tmpl  = (const float*)d_in[3];
    const float* wq_cw = (const float*)d_in[4];
    const float* wq_cb = (const float*)d_in[5];
    const float* wq_b  = (const float*)d_in[6];
    const float* wk_cw = (const float*)d_in[7];
    const float* wk_cb = (const float*)d_in[8];
    const float* wk_b  = (const float*)d_in[9];
    const float* wv_cw = (const float*)d_in[10];
    const float* wv_cb = (const float*)d_in[11];
    const float* wv_b  = (const float*)d_in[12];

    char* ws = (char*)d_ws;
    u16* Wh = (u16*)(ws);                    //  6,291,456 B
    u16* Wl = (u16*)(ws + 6291456);          //  6,291,456 B
    u16* Qh = (u16*)(ws + 12582912);         //  8,388,608 B each below
    u16* Ql = (u16*)(ws + 20971520);
    u16* Kh = (u16*)(ws + 29360128);
    u16* Kl = (u16*)(ws + 37748736);
    u16* Vb = (u16*)(ws + 46137344);
    u16* Vt = (u16*)(ws + 54525952);         // ends at 62,914,560
    float* out = (float*)d_out;

    conv_weight_kernel<<<dim3(DIM / 256, DIM, 3), 256, 0, stream>>>(
        tmpl, wq_cw, wq_cb, wk_cw, wk_cb, wv_cw, wv_cb, Wh, Wl);

    qkv_mfma_gemm<<<dim3(DIM / 128, NROWS / 128, 3), 256, 0, stream>>>(
        query, key_, value, Wh, Wl, wq_b, wk_b, wv_b, Qh, Ql, Kh, Kl, Vb);

    vt_kernel<<<dim3(SLEN / 64, NHEAD, BATCH), 256, 0, stream>>>(Vb, Vt);

    attn_mfma_kernel<<<dim3(SLEN / 64, NHEAD, BATCH), 256, 0, stream>>>(
        Qh, Ql, Kh, Kl, Vt, out);
}

// Round 4
// 389.733 us; speedup vs baseline: 2.5651x; 1.0549x over previous
//
#include <hip/hip_runtime.h>
#include <math.h>

#define TDIM   1032
#define DIM    1024
#define SLEN   2048
#define BATCH  2
#define NROWS  (SLEN*BATCH)   // 4096
#define NHEAD  16
#define HD     64

typedef unsigned short u16;
typedef short short8 __attribute__((ext_vector_type(8)));
typedef float f32x4  __attribute__((ext_vector_type(4)));

__device__ inline u16 f2bf_rne(float x) {
    union { float f; unsigned u; } v; v.f = x;
    unsigned r = v.u + 0x7fffu + ((v.u >> 16) & 1u);
    return (u16)(r >> 16);
}
__device__ inline float bf2f(u16 b) {
    union { unsigned u; float f; } v; v.u = ((unsigned)b) << 16;
    return v.f;
}
__device__ inline void dma16(const u16* g, u16* l) {
    __builtin_amdgcn_global_load_lds(
        (const __attribute__((address_space(1))) void*)g,
        (__attribute__((address_space(3))) void*)l, 16, 0, 0);
}

// ---------------------------------------------------------------------------
// Kernel 1: conv 9x9 over template -> Wh/Wl bf16 hi/lo split directly.
// ---------------------------------------------------------------------------
__global__ __launch_bounds__(256) void conv_weight_kernel(
    const float* __restrict__ tmpl,
    const float* __restrict__ cw0, const float* __restrict__ cb0,
    const float* __restrict__ cw1, const float* __restrict__ cb1,
    const float* __restrict__ cw2, const float* __restrict__ cb2,
    u16* __restrict__ Wh, u16* __restrict__ Wl)
{
    int t = blockIdx.z;
    const float* cw = (t == 0) ? cw0 : ((t == 1) ? cw1 : cw2);
    const float* cb = (t == 0) ? cb0 : ((t == 1) ? cb1 : cb2);
    __shared__ float scw[81];
    if (threadIdx.x < 81) scw[threadIdx.x] = cw[threadIdx.x];
    __syncthreads();
    int i = blockIdx.x * 256 + threadIdx.x;
    int o = blockIdx.y;
    float acc = cb[0];
    #pragma unroll
    for (int dy = 0; dy < 9; ++dy) {
        const float* trow = tmpl + (size_t)(o + dy) * TDIM + i;
        #pragma unroll
        for (int dx = 0; dx < 9; ++dx)
            acc = fmaf(scw[dy * 9 + dx], trow[dx], acc);
    }
    size_t idx = (size_t)t * DIM * DIM + (size_t)o * DIM + i;
    u16 h = f2bf_rne(acc);
    Wh[idx] = h;
    Wl[idx] = f2bf_rne(acc - bf2f(h));
}

// ---------------------------------------------------------------------------
// Kernel 2: MFMA GEMM (unchanged from R3 — verified at ~150us).
// ---------------------------------------------------------------------------
__global__ __launch_bounds__(256, 3) void qkv_mfma_gemm(
    const float* __restrict__ x0, const float* __restrict__ x1,
    const float* __restrict__ x2,
    const u16* __restrict__ Whg, const u16* __restrict__ Wlg,
    const float* __restrict__ b0, const float* __restrict__ b1,
    const float* __restrict__ b2,
    u16* __restrict__ Qh, u16* __restrict__ Ql,
    u16* __restrict__ Kh, u16* __restrict__ Kl,
    u16* __restrict__ Vb)
{
    int t = blockIdx.z;
    const float* X    = (t == 0) ? x0 : ((t == 1) ? x1 : x2);
    const u16* Bh_g   = Whg + (size_t)t * DIM * DIM;
    const u16* Bl_g   = Wlg + (size_t)t * DIM * DIM;
    const float* bias = (t == 0) ? b0 : ((t == 1) ? b1 : b2);

    __shared__ __align__(16) u16 lds[16384];
    u16* sAh = lds;
    u16* sAl = lds + 4096;
    u16* sBh = lds + 8192;
    u16* sBl = lds + 12288;

    int tid = threadIdx.x;
    int w = tid >> 6, lane = tid & 63;
    int c = lane & 15, quad = lane >> 4;
    int m0 = blockIdx.y * 128, n0 = blockIdx.x * 128;
    int mh = (w >> 1) * 64, nh = (w & 1) * 64;

    int arow = w * 32 + (lane & 31);
    int acol = (lane >> 5) * 16;
    const float* aptr = X + (size_t)(m0 + arow) * DIM + acol;

    int srow = lane >> 2, sgr = lane & 3;

    f32x4 acc[4][4];
    #pragma unroll
    for (int i = 0; i < 4; ++i)
        #pragma unroll
        for (int j = 0; j < 4; ++j)
            #pragma unroll
            for (int r = 0; r < 4; ++r) acc[i][j][r] = 0.0f;

    float bias_v[4];
    #pragma unroll
    for (int tn = 0; tn < 4; ++tn) bias_v[tn] = bias[n0 + nh + tn * 16 + c];

    float4 xa[4];
    #pragma unroll
    for (int i = 0; i < 2; ++i) {
        int rb = w * 32 + i * 16;
        const u16* gh = Bh_g + (size_t)(n0 + rb + srow) * DIM + sgr * 8;
        const u16* gl = Bl_g + (size_t)(n0 + rb + srow) * DIM + sgr * 8;
        dma16(gh, sBh + rb * 32);
        dma16(gl, sBl + rb * 32);
    }
    #pragma unroll
    for (int j = 0; j < 4; ++j) xa[j] = *(const float4*)(aptr + j * 4);

    for (int it = 0; it < 32; ++it) {
        #pragma unroll
        for (int g = 0; g < 2; ++g) {
            float v[8] = { xa[2*g].x, xa[2*g].y, xa[2*g].z, xa[2*g].w,
                           xa[2*g+1].x, xa[2*g+1].y, xa[2*g+1].z, xa[2*g+1].w };
            short8 hv, lv;
            #pragma unroll
            for (int e = 0; e < 8; ++e) {
                u16 h = f2bf_rne(v[e]);
                hv[e] = (short)h;
                lv[e] = (short)f2bf_rne(v[e] - bf2f(h));
            }
            *(short8*)(sAh + arow * 32 + acol + g * 8) = hv;
            *(short8*)(sAl + arow * 32 + acol + g * 8) = lv;
        }
        __syncthreads();

        short8 ah[4], al[4], bh[4], bl[4];
        #pragma unroll
        for (int tt = 0; tt < 4; ++tt) {
            int mi = (mh + tt * 16 + c) * 32 + quad * 8;
            ah[tt] = *(short8*)(sAh + mi);
            al[tt] = *(short8*)(sAl + mi);
            int ni = (nh + tt * 16 + c) * 32 + quad * 8;
            bh[tt] = *(short8*)(sBh + ni);
            bl[tt] = *(short8*)(sBl + ni);
        }
        __syncthreads();

        if (it < 31) {
            int kg = (it + 1) * 4;
            #pragma unroll
            for (int i = 0; i < 2; ++i) {
                int rb = w * 32 + i * 16;
                const u16* gh = Bh_g + (size_t)(n0 + rb + srow) * DIM + (kg + sgr) * 8;
                const u16* gl = Bl_g + (size_t)(n0 + rb + srow) * DIM + (kg + sgr) * 8;
                dma16(gh, sBh + rb * 32);
                dma16(gl, sBl + rb * 32);
            }
            #pragma unroll
            for (int j = 0; j < 4; ++j)
                xa[j] = *(const float4*)(aptr + (it + 1) * 32 + j * 4);
        }

        #pragma unroll
        for (int tm = 0; tm < 4; ++tm)
            #pragma unroll
            for (int tn = 0; tn < 4; ++tn) {
                acc[tm][tn] = __builtin_amdgcn_mfma_f32_16x16x32_bf16(
                    ah[tm], bh[tn], acc[tm][tn], 0, 0, 0);
                acc[tm][tn] = __builtin_amdgcn_mfma_f32_16x16x32_bf16(
                    ah[tm], bl[tn], acc[tm][tn], 0, 0, 0);
                acc[tm][tn] = __builtin_amdgcn_mfma_f32_16x16x32_bf16(
                    al[tm], bh[tn], acc[tm][tn], 0, 0, 0);
            }
    }

    if (t < 2) {
        u16* Yh = (t == 0) ? Qh : Kh;
        u16* Yl = (t == 0) ? Ql : Kl;
        #pragma unroll
        for (int tm = 0; tm < 4; ++tm)
            #pragma unroll
            for (int r = 0; r < 4; ++r) {
                int m = m0 + mh + tm * 16 + quad * 4 + r;
                #pragma unroll
                for (int tn = 0; tn < 4; ++tn) {
                    int n = n0 + nh + tn * 16 + c;
                    float o = acc[tm][tn][r] + bias_v[tn];
                    u16 h = f2bf_rne(o);
                    Yh[(size_t)m * DIM + n] = h;
                    Yl[(size_t)m * DIM + n] = f2bf_rne(o - bf2f(h));
                }
            }
    } else {
        #pragma unroll
        for (int tm = 0; tm < 4; ++tm)
            #pragma unroll
            for (int r = 0; r < 4; ++r) {
                int m = m0 + mh + tm * 16 + quad * 4 + r;
                #pragma unroll
                for (int tn = 0; tn < 4; ++tn) {
                    int n = n0 + nh + tn * 16 + c;
                    Vb[(size_t)m * DIM + n] = f2bf_rne(acc[tm][tn][r] + bias_v[tn]);
                }
            }
    }
}

// ---------------------------------------------------------------------------
// Kernel 3: V bf16 [s*B+b][h*64+d] -> Vt bf16 [b][h][d][s]
// ---------------------------------------------------------------------------
__global__ __launch_bounds__(256) void vt_kernel(
    const u16* __restrict__ Vb, u16* __restrict__ Vt)
{
    int b = blockIdx.z, h = blockIdx.y, s0 = blockIdx.x * 64;
    __shared__ __align__(16) u16 tile[64][80];
    int tid = threadIdx.x;
    int sl = tid >> 2, d0 = (tid & 3) * 16;
    const u16* src = Vb + (size_t)((s0 + sl) * BATCH + b) * DIM + h * HD + d0;
    short8 v0 = *(const short8*)src;
    short8 v1 = *(const short8*)(src + 8);
    #pragma unroll
    for (int j = 0; j < 8; ++j) {
        tile[d0 + j][sl] = (u16)v0[j];
        tile[d0 + 8 + j][sl] = (u16)v1[j];
    }
    __syncthreads();
    int d = tid >> 2, sc0 = (tid & 3) * 16;
    u16* dst = Vt + (size_t)((b * NHEAD + h) * HD + d) * SLEN + s0 + sc0;
    *(short8*)dst = *(const short8*)&tile[d][sc0];
    *(short8*)(dst + 8) = *(const short8*)&tile[d][sc0 + 8];
}

// ---------------------------------------------------------------------------
// Kernel 4: MFMA flash attention v2.
// Block = (b, h, 128-query tile), 4 waves; wave w owns rows w*32..w*32+31
// as two 16-row A-frag subtiles. K/V tiles (64 keys) double-buffered in
// XOR-swizzled LDS, staged via global_load_lds w=16, ONE barrier per k-tile.
// ---------------------------------------------------------------------------
__global__ __launch_bounds__(256) void attn_mfma_kernel(
    const u16* __restrict__ Qh, const u16* __restrict__ Ql,
    const u16* __restrict__ Kh, const u16* __restrict__ Kl,
    const u16* __restrict__ Vt, float* __restrict__ out)
{
    int b = blockIdx.z, h = blockIdx.y;
    int q0 = blockIdx.x * 128;
    int tid = threadIdx.x;
    int w = tid >> 6, lane = tid & 63;
    int c = lane & 15, quad = lane >> 4;

    // [buf][tile: Kh,Kl,Vt][64 rows x 8 swizzled 16B-chunks]
    __shared__ __align__(16) u16 sbuf[2][3][4096];
    __shared__ __align__(16) u16 sP[4][2048];   // per-wave 32x64, swizzled

    // --- Q fragments: 2 subtiles x 2 k-steps, hi/lo ---
    short8 qhf[2][2], qlf[2][2];
    #pragma unroll
    for (int u = 0; u < 2; ++u) {
        int s = q0 + w * 32 + u * 16 + c;
        size_t base = (size_t)(s * BATCH + b) * DIM + h * HD + quad * 8;
        qhf[u][0] = *(const short8*)(Qh + base);
        qhf[u][1] = *(const short8*)(Qh + base + 32);
        qlf[u][0] = *(const short8*)(Ql + base);
        qlf[u][1] = *(const short8*)(Ql + base + 32);
    }

    f32x4 acc[2][4];
    #pragma unroll
    for (int u = 0; u < 2; ++u)
        #pragma unroll
        for (int i = 0; i < 4; ++i)
            #pragma unroll
            for (int r = 0; r < 4; ++r) acc[u][i][r] = 0.0f;
    float m_run[2][4], l_run[2][4];
    #pragma unroll
    for (int u = 0; u < 2; ++u)
        #pragma unroll
        for (int r = 0; r < 4; ++r) { m_run[u][r] = -1e38f; l_run[u][r] = 0.0f; }

    const float cs = 0.125f * 1.44269504f;

    // DMA lane decode: lane l -> tile row i*8+r3, source 16B-chunk sw
    int r3 = lane >> 3, c3 = lane & 7;
    int sw = c3 ^ r3;
    const size_t bhofs = (size_t)(b * NHEAD + h) * HD;

    // macro: stage k-tile at n0v into sbuf[bufv] (each wave: 6 DMA instrs)
    #define ISSUE_DMA(n0v, bufv) do {                                          \
        _Pragma("unroll")                                                      \
        for (int j = 0; j < 2; ++j) {                                          \
            int i_ = 2 * w + j;                                                \
            int row_ = i_ * 8 + r3;                                            \
            size_t gk = (size_t)(((n0v) + row_) * BATCH + b) * DIM + h * HD + sw * 8; \
            dma16(Kh + gk, &sbuf[bufv][0][i_ * 512]);                          \
            dma16(Kl + gk, &sbuf[bufv][1][i_ * 512]);                          \
            size_t gv = (bhofs + row_) * SLEN + (n0v) + sw * 8;                \
            dma16(Vt + gv, &sbuf[bufv][2][i_ * 512]);                          \
        }                                                                      \
    } while (0)

    ISSUE_DMA(0, 0);

    for (int it = 0; it < 32; ++it) {
        int cur = it & 1;
        __syncthreads();                       // DMA(it) landed; buf[cur^1] free
        if (it < 31) ISSUE_DMA((it + 1) * 64, cur ^ 1);

        const u16* bKh = sbuf[cur][0];
        const u16* bKl = sbuf[cur][1];
        const u16* bVt = sbuf[cur][2];

        // ---- S = Q K^T : per ct read K frags once, reuse for both subtiles ----
        f32x4 sc[2][4];
        #pragma unroll
        for (int ct = 0; ct < 4; ++ct) {
            int row = ct * 16 + c, rw = row & 7;
            int kb = row * 64;
            short8 kh0 = *(const short8*)(bKh + kb + ((quad ^ rw) * 8));
            short8 kh1 = *(const short8*)(bKh + kb + (((4 + quad) ^ rw) * 8));
            short8 kl0 = *(const short8*)(bKl + kb + ((quad ^ rw) * 8));
            short8 kl1 = *(const short8*)(bKl + kb + (((4 + quad) ^ rw) * 8));
            #pragma unroll
            for (int u = 0; u < 2; ++u) {
                f32x4 s = {0.0f, 0.0f, 0.0f, 0.0f};
                s = __builtin_amdgcn_mfma_f32_16x16x32_bf16(qhf[u][0], kh0, s, 0, 0, 0);
                s = __builtin_amdgcn_mfma_f32_16x16x32_bf16(qhf[u][1], kh1, s, 0, 0, 0);
                s = __builtin_amdgcn_mfma_f32_16x16x32_bf16(qhf[u][0], kl0, s, 0, 0, 0);
                s = __builtin_amdgcn_mfma_f32_16x16x32_bf16(qhf[u][1], kl1, s, 0, 0, 0);
                s = __builtin_amdgcn_mfma_f32_16x16x32_bf16(qlf[u][0], kh0, s, 0, 0, 0);
                s = __builtin_amdgcn_mfma_f32_16x16x32_bf16(qlf[u][1], kh1, s, 0, 0, 0);
                sc[u][ct] = s;
            }
        }

        // ---- online softmax ----
        #pragma unroll
        for (int u = 0; u < 2; ++u) {
            #pragma unroll
            for (int r = 0; r < 4; ++r) {
                float t = fmaxf(fmaxf(sc[u][0][r], sc[u][1][r]),
                                fmaxf(sc[u][2][r], sc[u][3][r]));
                t = fmaxf(t, __shfl_xor(t, 1));
                t = fmaxf(t, __shfl_xor(t, 2));
                t = fmaxf(t, __shfl_xor(t, 4));
                t = fmaxf(t, __shfl_xor(t, 8));
                float mnew = fmaxf(m_run[u][r], t);
                float al = exp2f((m_run[u][r] - mnew) * cs);
                m_run[u][r] = mnew;
                float rs = 0.0f;
                #pragma unroll
                for (int ct = 0; ct < 4; ++ct) {
                    float p = exp2f((sc[u][ct][r] - mnew) * cs);
                    sc[u][ct][r] = p;
                    rs += p;
                }
                rs += __shfl_xor(rs, 1);
                rs += __shfl_xor(rs, 2);
                rs += __shfl_xor(rs, 4);
                rs += __shfl_xor(rs, 8);
                l_run[u][r] = l_run[u][r] * al + rs;
                #pragma unroll
                for (int ctd = 0; ctd < 4; ++ctd) acc[u][ctd][r] *= al;
            }
        }

        // ---- P (C-layout) -> bf16 -> wave-private swizzled LDS ----
        u16* wp = sP[w];
        #pragma unroll
        for (int u = 0; u < 2; ++u)
            #pragma unroll
            for (int r = 0; r < 4; ++r) {
                int row = u * 16 + quad * 4 + r;
                int rw = (row + (row >> 3)) & 7;
                #pragma unroll
                for (int ct = 0; ct < 4; ++ct) {
                    int chunk = ct * 2 + (c >> 3);
                    wp[row * 64 + ((chunk ^ rw) * 8) + (c & 7)] =
                        f2bf_rne(sc[u][ct][r]);
                }
            }

        short8 pf[2][2];
        #pragma unroll
        for (int u = 0; u < 2; ++u) {
            int row = u * 16 + c;
            int rw = (row + (row >> 3)) & 7;
            pf[u][0] = *(const short8*)(wp + row * 64 + ((quad ^ rw) * 8));
            pf[u][1] = *(const short8*)(wp + row * 64 + (((4 + quad) ^ rw) * 8));
        }

        // ---- O += P V ----
        #pragma unroll
        for (int ctd = 0; ctd < 4; ++ctd) {
            int row = ctd * 16 + c, rw = row & 7;
            int vb = row * 64;
            short8 v0 = *(const short8*)(bVt + vb + ((quad ^ rw) * 8));
            short8 v1 = *(const short8*)(bVt + vb + (((4 + quad) ^ rw) * 8));
            #pragma unroll
            for (int u = 0; u < 2; ++u) {
                acc[u][ctd] = __builtin_amdgcn_mfma_f32_16x16x32_bf16(
                    pf[u][0], v0, acc[u][ctd], 0, 0, 0);
                acc[u][ctd] = __builtin_amdgcn_mfma_f32_16x16x32_bf16(
                    pf[u][1], v1, acc[u][ctd], 0, 0, 0);
            }
        }
    }
    #undef ISSUE_DMA

    // ---- epilogue ----
    #pragma unroll
    for (int u = 0; u < 2; ++u) {
        float rl[4];
        #pragma unroll
        for (int r = 0; r < 4; ++r) rl[r] = 1.0f / l_run[u][r];
        #pragma unroll
        for (int ctd = 0; ctd < 4; ++ctd)
            #pragma unroll
            for (int r = 0; r < 4; ++r) {
                int s = q0 + w * 32 + u * 16 + quad * 4 + r;
                out[(size_t)(s * BATCH + b) * DIM + h * HD + ctd * 16 + c] =
                    acc[u][ctd][r] * rl[r];
            }
    }
}

// ---------------------------------------------------------------------------
extern "C" void kernel_launch(void* const* d_in, const int* in_sizes, int n_in,
                              void* d_out, int out_size, void* d_ws, size_t ws_size,
                              hipStream_t stream)
{
    const float* query = (const float*)d_in[0];
    const float* key_  = (const float*)d_in[1];
    const float* value = (const float*)d_in[2];
    const float* tmpl  = (const float*)d_in[3];
    const float* wq_cw = (const float*)d_in[4];
    const float* wq_cb = (const float*)d_in[5];
    const float* wq_b  = (const float*)d_in[6];
    const float* wk_cw = (const float*)d_in[7];
    const float* wk_cb = (const float*)d_in[8];
    const float* wk_b  = (const float*)d_in[9];
    const float* wv_cw = (const float*)d_in[10];
    const float* wv_cb = (const float*)d_in[11];
    const float* wv_b  = (const float*)d_in[12];

    char* ws = (char*)d_ws;
    u16* Wh = (u16*)(ws);
    u16* Wl = (u16*)(ws + 6291456);
    u16* Qh = (u16*)(ws + 12582912);
    u16* Ql = (u16*)(ws + 20971520);
    u16* Kh = (u16*)(ws + 29360128);
    u16* Kl = (u16*)(ws + 37748736);
    u16* Vb = (u16*)(ws + 46137344);
    u16* Vt = (u16*)(ws + 54525952);
    float* out = (float*)d_out;

    conv_weight_kernel<<<dim3(DIM / 256, DIM, 3), 256, 0, stream>>>(
        tmpl, wq_cw, wq_cb, wk_cw, wk_cb, wv_cw, wv_cb, Wh, Wl);

    qkv_mfma_gemm<<<dim3(DIM / 128, NROWS / 128, 3), 256, 0, stream>>>(
        query, key_, value, Wh, Wl, wq_b, wk_b, wv_b, Qh, Ql, Kh, Kl, Vb);

    vt_kernel<<<dim3(SLEN / 64, NHEAD, BATCH), 256, 0, stream>>>(Vb, Vt);

    attn_mfma_kernel<<<dim3(SLEN / 128, NHEAD, BATCH), 256, 0, stream>>>(
        Qh, Ql, Kh, Kl, Vt, out);
}

// Round 7
// 339.213 us; speedup vs baseline: 2.9471x; 1.1489x over previous
//
#include <hip/hip_runtime.h>
#include <math.h>

#define TDIM   1032
#define DIM    1024
#define SLEN   2048
#define BATCH  2
#define NROWS  (SLEN*BATCH)   // 4096
#define NHEAD  16
#define HD     64

typedef unsigned short u16;
typedef short short8 __attribute__((ext_vector_type(8)));
typedef short bf16x4 __attribute__((ext_vector_type(4)));
typedef float f32x4  __attribute__((ext_vector_type(4)));

#define CSCALE 0.18033688011112042f   // 0.125 * log2(e), folded into Q

__device__ inline unsigned fbits(float x) {
    union { float f; unsigned u; } v; v.f = x; return v.u;
}
__device__ inline float asfloat(unsigned u) {
    union { unsigned u; float f; } v; v.u = u; return v.f;
}
__device__ inline u16 f2bf_rne(float x) {
    unsigned u = fbits(x);
    unsigned r = u + 0x7fffu + ((u >> 16) & 1u);
    return (u16)(r >> 16);
}
__device__ inline float bf2f(u16 b) { return asfloat(((unsigned)b) << 16); }
__device__ inline void dma16(const u16* g, u16* l) {
    __builtin_amdgcn_global_load_lds(
        (const __attribute__((address_space(1))) void*)g,
        (__attribute__((address_space(3))) void*)l, 16, 0, 0);
}

// ---------------------------------------------------------------------------
// Kernel 1: conv 9x9 over template -> Wh/Wl bf16 hi/lo split directly.
// ---------------------------------------------------------------------------
__global__ __launch_bounds__(256) void conv_weight_kernel(
    const float* __restrict__ tmpl,
    const float* __restrict__ cw0, const float* __restrict__ cb0,
    const float* __restrict__ cw1, const float* __restrict__ cb1,
    const float* __restrict__ cw2, const float* __restrict__ cb2,
    u16* __restrict__ Wh, u16* __restrict__ Wl)
{
    int t = blockIdx.z;
    const float* cw = (t == 0) ? cw0 : ((t == 1) ? cw1 : cw2);
    const float* cb = (t == 0) ? cb0 : ((t == 1) ? cb1 : cb2);
    __shared__ float scw[81];
    if (threadIdx.x < 81) scw[threadIdx.x] = cw[threadIdx.x];
    __syncthreads();
    int i = blockIdx.x * 256 + threadIdx.x;
    int o = blockIdx.y;
    float acc = cb[0];
    #pragma unroll
    for (int dy = 0; dy < 9; ++dy) {
        const float* trow = tmpl + (size_t)(o + dy) * TDIM + i;
        #pragma unroll
        for (int dx = 0; dx < 9; ++dx)
            acc = fmaf(scw[dy * 9 + dx], trow[dx], acc);
    }
    size_t idx = (size_t)t * DIM * DIM + (size_t)o * DIM + i;
    u16 h = f2bf_rne(acc);
    Wh[idx] = h;
    Wl[idx] = f2bf_rne(acc - bf2f(h));
}

// ---------------------------------------------------------------------------
// Kernel 2: MFMA GEMM  Y[t] = X[t] @ W[t]^T + b[t]  (3-term bf16 hi/lo).
// Trunc-hi split, SAFE element-wise vector writes (no unsigned* punning —
// strict-aliasing DCE was the R5/R6 failure). Q epilogue pre-scaled CSCALE.
// ---------------------------------------------------------------------------
__global__ __launch_bounds__(256, 3) void qkv_mfma_gemm(
    const float* __restrict__ x0, const float* __restrict__ x1,
    const float* __restrict__ x2,
    const u16* __restrict__ Whg, const u16* __restrict__ Wlg,
    const float* __restrict__ b0, const float* __restrict__ b1,
    const float* __restrict__ b2,
    u16* __restrict__ Qh, u16* __restrict__ Ql,
    u16* __restrict__ Kh, u16* __restrict__ Kl,
    u16* __restrict__ Vb)
{
    int t = blockIdx.z;
    const float* X    = (t == 0) ? x0 : ((t == 1) ? x1 : x2);
    const u16* Bh_g   = Whg + (size_t)t * DIM * DIM;
    const u16* Bl_g   = Wlg + (size_t)t * DIM * DIM;
    const float* bias = (t == 0) ? b0 : ((t == 1) ? b1 : b2);

    __shared__ __align__(16) u16 lds[16384];
    u16* sAh = lds;
    u16* sAl = lds + 4096;
    u16* sBh = lds + 8192;
    u16* sBl = lds + 12288;

    int tid = threadIdx.x;
    int w = tid >> 6, lane = tid & 63;
    int c = lane & 15, quad = lane >> 4;
    int m0 = blockIdx.y * 128, n0 = blockIdx.x * 128;
    int mh = (w >> 1) * 64, nh = (w & 1) * 64;

    int arow = w * 32 + (lane & 31);
    int acol = (lane >> 5) * 16;
    const float* aptr = X + (size_t)(m0 + arow) * DIM + acol;

    int srow = lane >> 2, sgr = lane & 3;

    f32x4 acc[4][4];
    #pragma unroll
    for (int i = 0; i < 4; ++i)
        #pragma unroll
        for (int j = 0; j < 4; ++j)
            #pragma unroll
            for (int r = 0; r < 4; ++r) acc[i][j][r] = 0.0f;

    float bias_v[4];
    #pragma unroll
    for (int tn = 0; tn < 4; ++tn) bias_v[tn] = bias[n0 + nh + tn * 16 + c];

    float4 xa[4];
    #pragma unroll
    for (int i = 0; i < 2; ++i) {
        int rb = w * 32 + i * 16;
        const u16* gh = Bh_g + (size_t)(n0 + rb + srow) * DIM + sgr * 8;
        const u16* gl = Bl_g + (size_t)(n0 + rb + srow) * DIM + sgr * 8;
        dma16(gh, sBh + rb * 32);
        dma16(gl, sBl + rb * 32);
    }
    #pragma unroll
    for (int j = 0; j < 4; ++j) xa[j] = *(const float4*)(aptr + j * 4);

    for (int it = 0; it < 32; ++it) {
        // ---- A regs -> trunc-hi/lo bf16 (element-wise, aliasing-safe) ----
        #pragma unroll
        for (int g = 0; g < 2; ++g) {
            float v[8] = { xa[2*g].x, xa[2*g].y, xa[2*g].z, xa[2*g].w,
                           xa[2*g+1].x, xa[2*g+1].y, xa[2*g+1].z, xa[2*g+1].w };
            short8 hv, lv;
            #pragma unroll
            for (int e = 0; e < 8; ++e) {
                unsigned u = fbits(v[e]);
                hv[e] = (short)(u >> 16);
                float l = v[e] - asfloat(u & 0xffff0000u);
                lv[e] = (short)(fbits(l) >> 16);
            }
            *(short8*)(sAh + arow * 32 + acol + g * 8) = hv;
            *(short8*)(sAl + arow * 32 + acol + g * 8) = lv;
        }
        __syncthreads();

        short8 ah[4], al[4], bh[4], bl[4];
        #pragma unroll
        for (int tt = 0; tt < 4; ++tt) {
            int mi = (mh + tt * 16 + c) * 32 + quad * 8;
            ah[tt] = *(short8*)(sAh + mi);
            al[tt] = *(short8*)(sAl + mi);
            int ni = (nh + tt * 16 + c) * 32 + quad * 8;
            bh[tt] = *(short8*)(sBh + ni);
            bl[tt] = *(short8*)(sBl + ni);
        }
        __syncthreads();

        if (it < 31) {
            int kg = (it + 1) * 4;
            #pragma unroll
            for (int i = 0; i < 2; ++i) {
                int rb = w * 32 + i * 16;
                const u16* gh = Bh_g + (size_t)(n0 + rb + srow) * DIM + (kg + sgr) * 8;
                const u16* gl = Bl_g + (size_t)(n0 + rb + srow) * DIM + (kg + sgr) * 8;
                dma16(gh, sBh + rb * 32);
                dma16(gl, sBl + rb * 32);
            }
            #pragma unroll
            for (int j = 0; j < 4; ++j)
                xa[j] = *(const float4*)(aptr + (it + 1) * 32 + j * 4);
        }

        #pragma unroll
        for (int tm = 0; tm < 4; ++tm)
            #pragma unroll
            for (int tn = 0; tn < 4; ++tn) {
                acc[tm][tn] = __builtin_amdgcn_mfma_f32_16x16x32_bf16(
                    ah[tm], bh[tn], acc[tm][tn], 0, 0, 0);
                acc[tm][tn] = __builtin_amdgcn_mfma_f32_16x16x32_bf16(
                    ah[tm], bl[tn], acc[tm][tn], 0, 0, 0);
                acc[tm][tn] = __builtin_amdgcn_mfma_f32_16x16x32_bf16(
                    al[tm], bh[tn], acc[tm][tn], 0, 0, 0);
            }
    }

    // ---- epilogue: trunc-hi/lo split; Q pre-scaled by CSCALE ----
    if (t < 2) {
        u16* Yh = (t == 0) ? Qh : Kh;
        u16* Yl = (t == 0) ? Ql : Kl;
        float qs = (t == 0) ? CSCALE : 1.0f;
        #pragma unroll
        for (int tm = 0; tm < 4; ++tm)
            #pragma unroll
            for (int r = 0; r < 4; ++r) {
                int m = m0 + mh + tm * 16 + quad * 4 + r;
                #pragma unroll
                for (int tn = 0; tn < 4; ++tn) {
                    int n = n0 + nh + tn * 16 + c;
                    float o = (acc[tm][tn][r] + bias_v[tn]) * qs;
                    unsigned bo = fbits(o);
                    Yh[(size_t)m * DIM + n] = (u16)(bo >> 16);
                    float l = o - asfloat(bo & 0xffff0000u);
                    Yl[(size_t)m * DIM + n] = (u16)(fbits(l) >> 16);
                }
            }
    } else {
        #pragma unroll
        for (int tm = 0; tm < 4; ++tm)
            #pragma unroll
            for (int r = 0; r < 4; ++r) {
                int m = m0 + mh + tm * 16 + quad * 4 + r;
                #pragma unroll
                for (int tn = 0; tn < 4; ++tn) {
                    int n = n0 + nh + tn * 16 + c;
                    Vb[(size_t)m * DIM + n] =
                        (u16)(fbits(acc[tm][tn][r] + bias_v[tn]) >> 16);
                }
            }
    }
}

// ---------------------------------------------------------------------------
// Kernel 3: V bf16 [s*B+b][h*64+d] -> Vt bf16 [b][h][d][s]
// ---------------------------------------------------------------------------
__global__ __launch_bounds__(256) void vt_kernel(
    const u16* __restrict__ Vb, u16* __restrict__ Vt)
{
    int b = blockIdx.z, h = blockIdx.y, s0 = blockIdx.x * 64;
    __shared__ __align__(16) u16 tile[64][80];
    int tid = threadIdx.x;
    int sl = tid >> 2, d0 = (tid & 3) * 16;
    const u16* src = Vb + (size_t)((s0 + sl) * BATCH + b) * DIM + h * HD + d0;
    short8 v0 = *(const short8*)src;
    short8 v1 = *(const short8*)(src + 8);
    #pragma unroll
    for (int j = 0; j < 8; ++j) {
        tile[d0 + j][sl] = (u16)v0[j];
        tile[d0 + 8 + j][sl] = (u16)v1[j];
    }
    __syncthreads();
    int d = tid >> 2, sc0 = (tid & 3) * 16;
    u16* dst = Vt + (size_t)((b * NHEAD + h) * HD + d) * SLEN + s0 + sc0;
    *(short8*)dst = *(const short8*)&tile[d][sc0];
    *(short8*)(dst + 8) = *(const short8*)&tile[d][sc0 + 8];
}

// ---------------------------------------------------------------------------
// Kernel 4: MFMA flash attention v4 — transposed scores + LDS P roundtrip.
// T = K·Q^T: lane holds T[key=ct*16+quad*4+r][q=c]. Per-lane softmax on
// row q=c (in-lane 16-max + shfl_xor 16/32). P -> bf16 (element-wise pack)
// -> wave-private swizzled LDS as 8B writes -> b128 A-frags for PV.
// ---------------------------------------------------------------------------
__global__ __launch_bounds__(256) void attn_mfma_kernel(
    const u16* __restrict__ Qh, const u16* __restrict__ Ql,
    const u16* __restrict__ Kh, const u16* __restrict__ Kl,
    const u16* __restrict__ Vt, float* __restrict__ out)
{
    int b = blockIdx.z, h = blockIdx.y;
    int q0 = blockIdx.x * 128;
    int tid = threadIdx.x;
    int w = tid >> 6, lane = tid & 63;
    int c = lane & 15, quad = lane >> 4;

    // [buf][tile: Kh,Kl,Vt][64 rows x 8 swizzled 16B-chunks] = 48 KB
    __shared__ __align__(16) u16 sbuf[2][3][4096];
    // wave-private P: 32 q-rows x 64 keys, chunk8-swizzled = 16 KB
    __shared__ __align__(16) u16 sP[4][2048];

    // --- Q fragments (B operands of K·Q^T) ---
    short8 qhf[2][2], qlf[2][2];
    #pragma unroll
    for (int u = 0; u < 2; ++u) {
        int s = q0 + w * 32 + u * 16 + c;
        size_t base = (size_t)(s * BATCH + b) * DIM + h * HD + quad * 8;
        qhf[u][0] = *(const short8*)(Qh + base);
        qhf[u][1] = *(const short8*)(Qh + base + 32);
        qlf[u][0] = *(const short8*)(Ql + base);
        qlf[u][1] = *(const short8*)(Ql + base + 32);
    }

    f32x4 acc[2][4];
    #pragma unroll
    for (int u = 0; u < 2; ++u)
        #pragma unroll
        for (int i = 0; i < 4; ++i)
            #pragma unroll
            for (int r = 0; r < 4; ++r) acc[u][i][r] = 0.0f;
    float m_run[2] = {-1e38f, -1e38f}, l_run[2] = {0.0f, 0.0f};

    int r3 = lane >> 3, c3 = lane & 7;
    int sw = c3 ^ r3;
    const size_t bhofs = (size_t)(b * NHEAD + h) * HD;

    #define ISSUE_DMA(n0v, bufv) do {                                          \
        _Pragma("unroll")                                                      \
        for (int j = 0; j < 2; ++j) {                                          \
            int i_ = 2 * w + j;                                                \
            int row_ = i_ * 8 + r3;                                            \
            size_t gk = (size_t)(((n0v) + row_) * BATCH + b) * DIM + h * HD + sw * 8; \
            dma16(Kh + gk, &sbuf[bufv][0][i_ * 512]);                          \
            dma16(Kl + gk, &sbuf[bufv][1][i_ * 512]);                          \
            size_t gv = (bhofs + row_) * SLEN + (n0v) + sw * 8;                \
            dma16(Vt + gv, &sbuf[bufv][2][i_ * 512]);                          \
        }                                                                      \
    } while (0)

    ISSUE_DMA(0, 0);

    for (int it = 0; it < 32; ++it) {
        int cur = it & 1;
        __syncthreads();                       // DMA(it) landed
        if (it < 31) ISSUE_DMA((it + 1) * 64, cur ^ 1);

        const u16* bKh = sbuf[cur][0];
        const u16* bKl = sbuf[cur][1];
        const u16* bVt = sbuf[cur][2];

        // ---- T = K·Q^T : lane gets T[key=ct*16+quad*4+r][q=c] ----
        f32x4 sc[2][4];
        #pragma unroll
        for (int ct = 0; ct < 4; ++ct) {
            int row = ct * 16 + c, rw = row & 7;
            int kb = row * 64;
            short8 kh0 = *(const short8*)(bKh + kb + ((quad ^ rw) * 8));
            short8 kh1 = *(const short8*)(bKh + kb + (((4 + quad) ^ rw) * 8));
            short8 kl0 = *(const short8*)(bKl + kb + ((quad ^ rw) * 8));
            short8 kl1 = *(const short8*)(bKl + kb + (((4 + quad) ^ rw) * 8));
            #pragma unroll
            for (int u = 0; u < 2; ++u) {
                f32x4 s = {0.0f, 0.0f, 0.0f, 0.0f};
                s = __builtin_amdgcn_mfma_f32_16x16x32_bf16(kh0, qhf[u][0], s, 0, 0, 0);
                s = __builtin_amdgcn_mfma_f32_16x16x32_bf16(kh1, qhf[u][1], s, 0, 0, 0);
                s = __builtin_amdgcn_mfma_f32_16x16x32_bf16(kh0, qlf[u][0], s, 0, 0, 0);
                s = __builtin_amdgcn_mfma_f32_16x16x32_bf16(kh1, qlf[u][1], s, 0, 0, 0);
                s = __builtin_amdgcn_mfma_f32_16x16x32_bf16(kl0, qhf[u][0], s, 0, 0, 0);
                s = __builtin_amdgcn_mfma_f32_16x16x32_bf16(kl1, qhf[u][1], s, 0, 0, 0);
                sc[u][ct] = s;
            }
        }

        // ---- online softmax (row q=c per lane) + pack P + write to sP ----
        u16* wp = sP[w];
        #pragma unroll
        for (int u = 0; u < 2; ++u) {
            float pm = sc[u][0][0];
            #pragma unroll
            for (int ct = 0; ct < 4; ++ct)
                #pragma unroll
                for (int r = 0; r < 4; ++r)
                    pm = fmaxf(pm, sc[u][ct][r]);
            pm = fmaxf(pm, __shfl_xor(pm, 16));
            pm = fmaxf(pm, __shfl_xor(pm, 32));
            float mnew = fmaxf(m_run[u], pm);
            float al = exp2f(m_run[u] - mnew);
            m_run[u] = mnew;
            float ps = 0.0f;
            int prow = (u * 16 + c) * 64;
            #pragma unroll
            for (int ct = 0; ct < 4; ++ct) {
                bf16x4 pk;
                #pragma unroll
                for (int r = 0; r < 4; ++r) {
                    float p = exp2f(sc[u][ct][r] - mnew);
                    ps += p;
                    pk[r] = (short)(fbits(p) >> 16);
                }
                int phys = (ct * 2 + (quad >> 1)) ^ (c & 7);
                *(bf16x4*)(wp + prow + phys * 8 + (quad & 1) * 4) = pk;
            }
            ps += __shfl_xor(ps, 16);
            ps += __shfl_xor(ps, 32);
            l_run[u] = l_run[u] * al + ps;

            // rescale O rows (acc row = quad*4+r; alpha lives at lane c=row)
            float alr[4];
            #pragma unroll
            for (int r = 0; r < 4; ++r)
                alr[r] = __shfl(al, (lane & 48) | (quad * 4 + r));
            #pragma unroll
            for (int ctd = 0; ctd < 4; ++ctd)
                #pragma unroll
                for (int r = 0; r < 4; ++r) acc[u][ctd][r] *= alr[r];
        }

        // ---- read P back as A-frags (b128), then O += P·V ----
        short8 pf[2][2];
        #pragma unroll
        for (int u = 0; u < 2; ++u) {
            int prow = (u * 16 + c) * 64, rw = c & 7;
            pf[u][0] = *(const short8*)(wp + prow + ((quad ^ rw) * 8));
            pf[u][1] = *(const short8*)(wp + prow + (((4 + quad) ^ rw) * 8));
        }
        #pragma unroll
        for (int ctd = 0; ctd < 4; ++ctd) {
            int vrow = ctd * 16 + c, vrw = vrow & 7;
            int vb = vrow * 64;
            short8 v0 = *(const short8*)(bVt + vb + ((quad ^ vrw) * 8));
            short8 v1 = *(const short8*)(bVt + vb + (((4 + quad) ^ vrw) * 8));
            #pragma unroll
            for (int u = 0; u < 2; ++u) {
                acc[u][ctd] = __builtin_amdgcn_mfma_f32_16x16x32_bf16(
                    pf[u][0], v0, acc[u][ctd], 0, 0, 0);
                acc[u][ctd] = __builtin_amdgcn_mfma_f32_16x16x32_bf16(
                    pf[u][1], v1, acc[u][ctd], 0, 0, 0);
            }
        }
    }
    #undef ISSUE_DMA

    // ---- epilogue: gather l per output row, divide, store ----
    #pragma unroll
    for (int u = 0; u < 2; ++u) {
        float rl[4];
        #pragma unroll
        for (int r = 0; r < 4; ++r)
            rl[r] = 1.0f / __shfl(l_run[u], (lane & 48) | (quad * 4 + r));
        #pragma unroll
        for (int ctd = 0; ctd < 4; ++ctd)
            #pragma unroll
            for (int r = 0; r < 4; ++r) {
                int s = q0 + w * 32 + u * 16 + quad * 4 + r;
                out[(size_t)(s * BATCH + b) * DIM + h * HD + ctd * 16 + c] =
                    acc[u][ctd][r] * rl[r];
            }
    }
}

// ---------------------------------------------------------------------------
extern "C" void kernel_launch(void* const* d_in, const int* in_sizes, int n_in,
                              void* d_out, int out_size, void* d_ws, size_t ws_size,
                              hipStream_t stream)
{
    const float* query = (const float*)d_in[0];
    const float* key_  = (const float*)d_in[1];
    const float* value = (const float*)d_in[2];
    const float* tmpl  = (const float*)d_in[3];
    const float* wq_cw = (const float*)d_in[4];
    const float* wq_cb = (const float*)d_in[5];
    const float* wq_b  = (const float*)d_in[6];
    const float* wk_cw = (const float*)d_in[7];
    const float* wk_cb = (const float*)d_in[8];
    const float* wk_b  = (const float*)d_in[9];
    const float* wv_cw = (const float*)d_in[10];
    const float* wv_cb = (const float*)d_in[11];
    const float* wv_b  = (const float*)d_in[12];

    char* ws = (char*)d_ws;
    u16* Wh = (u16*)(ws);
    u16* Wl = (u16*)(ws + 6291456);
    u16* Qh = (u16*)(ws + 12582912);
    u16* Ql = (u16*)(ws + 20971520);
    u16* Kh = (u16*)(ws + 29360128);
    u16* Kl = (u16*)(ws + 37748736);
    u16* Vb = (u16*)(ws + 46137344);
    u16* Vt = (u16*)(ws + 54525952);
    float* out = (float*)d_out;

    conv_weight_kernel<<<dim3(DIM / 256, DIM, 3), 256, 0, stream>>>(
        tmpl, wq_cw, wq_cb, wk_cw, wk_cb, wv_cw, wv_cb, Wh, Wl);

    qkv_mfma_gemm<<<dim3(DIM / 128, NROWS / 128, 3), 256, 0, stream>>>(
        query, key_, value, Wh, Wl, wq_b, wk_b, wv_b, Qh, Ql, Kh, Kl, Vb);

    vt_kernel<<<dim3(SLEN / 64, NHEAD, BATCH), 256, 0, stream>>>(Vb, Vt);

    attn_mfma_kernel<<<dim3(SLEN / 128, NHEAD, BATCH), 256, 0, stream>>>(
        Qh, Ql, Kh, Kl, Vt, out);
}